// Round 1
// baseline (464.122 us; speedup 1.0000x reference)
//
#include <hip/hip_runtime.h>
#include <hip/hip_bf16.h>
#include <cstdint>
#include <cstddef>

#define NN 8192
#define FIN 256
#define FOUT 64
#define ALPHA_SLOPE 0.2f
#define EXP_M10 4.5399929762484854e-05f   // exp(-10)
#define LOG2E 1.4426950408889634f

#define JC 8                              // j-chunks (one per XCD via blockIdx&7)
#define JSPAN (NN / JC)                   // 1024 cols per wave
#define NSTRIP (JSPAN / 128)              // 8 strips of 128 cols
#define CP 68                             // slab column pitch (floats): 64 num + den + pad

typedef short s16x8 __attribute__((ext_vector_type(8)));
typedef float f32x4 __attribute__((ext_vector_type(4)));
typedef int   i32x4 __attribute__((ext_vector_type(4)));

__device__ __forceinline__ unsigned short f2bf(float x) {
    union { float f; uint32_t u; } v; v.f = x;
    uint32_t u = v.u;
    return (unsigned short)((u + 0x7FFFu + ((u >> 16) & 1u)) >> 16);  // RNE
}

// packed bf16 pair: src0 -> low16, src1 -> high16 (RNE), single instruction
__device__ __forceinline__ unsigned int cvtpk(float lo, float hi) {
    unsigned int r;
    asm("v_cvt_pk_bf16_f32 %0, %1, %2" : "=v"(r) : "v"(lo), "v"(hi));
    return r;
}

// 2^x in one instruction (inputs pre-scaled by 1/ln2)
__device__ __forceinline__ float fexp2(float x) {
    float r;
    asm("v_exp_f32 %0, %1" : "=v"(r) : "v"(x));
    return r;
}

// ---------------- Kernel 0: bit-pack adj (the only full read of 268 MB) ----------
// Pure streaming, 32 waves/CU, ballot per 64 cols. 8192%64==0 so each 64-run is
// within one row; bit b of word w  <->  col w*32+b.
__global__ __launch_bounds__(256) void k_pack(
    const int* __restrict__ adj, unsigned int* __restrict__ mask)
{
    const int total  = NN * NN;                       // 67,108,864
    const int stride = gridDim.x * 256;               // multiple of 64
    int i = blockIdx.x * 256 + threadIdx.x;
    for (; i < total; i += 2 * stride) {
        int v0 = adj[i];
        int v1 = adj[i + stride];
        unsigned long long b0 = __ballot(v0 > 0);
        unsigned long long b1 = __ballot(v1 > 0);
        if ((threadIdx.x & 63) == 0) {
            *(uint2*)&mask[i >> 5] = make_uint2((unsigned)b0, (unsigned)(b0 >> 32));
            *(uint2*)&mask[(i + stride) >> 5] = make_uint2((unsigned)b1, (unsigned)(b1 >> 32));
        }
    }
}

// ---------------- Kernel 1: h = input@W, s1 = (h@a1)/ln2, s2 = (h@a2)/ln2,
//                  htg = bf16(h)^T --------------------------------------------------
__global__ __launch_bounds__(256) void k_h(
    const float* __restrict__ input, const float* __restrict__ W,
    const float* __restrict__ a,
    unsigned short* __restrict__ htg, float* __restrict__ s1, float* __restrict__ s2)
{
    __shared__ __align__(16) unsigned short tile[64][28];
    const int wid  = threadIdx.x >> 6;
    const int lane = threadIdx.x & 63;
    const int i0   = blockIdx.x * 16;
    const int r0   = wid * 4;
    const float* inb = input + (size_t)(i0 + r0) * FIN;

    float acc0 = 0.f, acc1 = 0.f, acc2 = 0.f, acc3 = 0.f;
    #pragma unroll 4
    for (int c = 0; c < FIN; c += 4) {
        float w0 = W[(c + 0) * FOUT + lane];
        float w1 = W[(c + 1) * FOUT + lane];
        float w2 = W[(c + 2) * FOUT + lane];
        float w3 = W[(c + 3) * FOUT + lane];
        float4 x0 = *(const float4*)(inb + 0 * FIN + c);
        float4 x1 = *(const float4*)(inb + 1 * FIN + c);
        float4 x2 = *(const float4*)(inb + 2 * FIN + c);
        float4 x3 = *(const float4*)(inb + 3 * FIN + c);
        acc0 = fmaf(x0.x, w0, fmaf(x0.y, w1, fmaf(x0.z, w2, fmaf(x0.w, w3, acc0))));
        acc1 = fmaf(x1.x, w0, fmaf(x1.y, w1, fmaf(x1.z, w2, fmaf(x1.w, w3, acc1))));
        acc2 = fmaf(x2.x, w0, fmaf(x2.y, w1, fmaf(x2.z, w2, fmaf(x2.w, w3, acc2))));
        acc3 = fmaf(x3.x, w0, fmaf(x3.y, w1, fmaf(x3.z, w2, fmaf(x3.w, w3, acc3))));
    }

    // scale by 1/ln2 so k_attn can use v_exp_f32 (2^x) with no per-element mul
    const float a1v = a[lane] * LOG2E, a2v = a[FOUT + lane] * LOG2E;
    float accs[4] = {acc0, acc1, acc2, acc3};
    #pragma unroll
    for (int r = 0; r < 4; ++r) {
        float v1 = accs[r] * a1v;
        float v2 = accs[r] * a2v;
        #pragma unroll
        for (int off = 32; off; off >>= 1) {
            v1 += __shfl_xor(v1, off);
            v2 += __shfl_xor(v2, off);
        }
        if (lane == 0) { s1[i0 + r0 + r] = v1; s2[i0 + r0 + r] = v2; }
        tile[lane][r0 + r] = f2bf(accs[r]);
    }
    __syncthreads();

    const int feat = threadIdx.x >> 2;
    const int cg   = (threadIdx.x & 3) * 4;
    uint2 q = *(const uint2*)&tile[feat][cg];
    *(uint2*)(htg + (size_t)feat * NN + i0 + cg) = q;
}

// ---------------- Kernel 2: barrier-free fused attention ---------------------------
// Grid 1024 blocks x 256 thr (4 waves). Wave = one 16-row x 1024-col tile.
// jc = blockIdx&7 pins each j-chunk to one XCD's L2 (htg slice = 128 KB resident).
// No LDS, no __syncthreads: w computed in-register directly in MFMA A-fragment
// layout; B-fragments read straight from L2-resident htg; adj via 1-bit mask.
__global__ __launch_bounds__(256, 4) void k_attn(
    const unsigned int* __restrict__ mask,
    const unsigned short* __restrict__ htg,
    const float* __restrict__ s1g, const float* __restrict__ s2g,
    float* __restrict__ slabs)
{
    const int t    = threadIdx.x;
    const int wb   = t >> 6;
    const int lane = t & 63;
    const int m    = lane & 15;
    const int quad = lane >> 4;
    const int jc   = blockIdx.x & (JC - 1);
    const int rt   = (blockIdx.x >> 3) * 4 + wb;    // 0..511 row-tiles
    const int row0 = rt * 16;
    const int row  = row0 + m;
    const int jbase = jc * JSPAN;

    const float s1v = s1g[row];
    const unsigned int*   mrow = mask + (size_t)row * (NN / 32) + (jbase >> 5);
    const float*          s2b  = s2g + jbase + quad * 8;
    const unsigned short* h0b  = htg + (size_t)(m +  0) * NN + jbase + quad * 8;
    const unsigned short* h1b  = htg + (size_t)(m + 16) * NN + jbase + quad * 8;
    const unsigned short* h2b  = htg + (size_t)(m + 32) * NN + jbase + quad * 8;
    const unsigned short* h3b  = htg + (size_t)(m + 48) * NN + jbase + quad * 8;

    const short bd = (m == 0) ? (short)0x3F80 : (short)0;   // bf16 1.0 at feat-col 0
    const s16x8 bden = {bd, bd, bd, bd, bd, bd, bd, bd};

    f32x4 acc0 = {0,0,0,0}, acc1 = {0,0,0,0}, acc2 = {0,0,0,0}, acc3 = {0,0,0,0};
    f32x4 accD = {0,0,0,0};

    for (int s = 0; s < NSTRIP; ++s) {
        const int c0 = s * 128;
        const i32x4 mw = *(const i32x4*)(mrow + (s << 2));   // 4 words = 4 kk blocks

        float4 sv[8];
        #pragma unroll
        for (int q = 0; q < 4; ++q) {
            sv[2*q]   = *(const float4*)(s2b + c0 + q * 32);
            sv[2*q+1] = *(const float4*)(s2b + c0 + q * 32 + 4);
        }

        #pragma unroll
        for (int kk = 0; kk < 4; ++kk) {
            const unsigned int mb = ((unsigned int)mw[kk]) >> (quad * 8);
            const float4 va = sv[2*kk], vb = sv[2*kk+1];

            float y0 = s1v + va.x, y1 = s1v + va.y, y2 = s1v + va.z, y3 = s1v + va.w;
            float y4 = s1v + vb.x, y5 = s1v + vb.y, y6 = s1v + vb.z, y7 = s1v + vb.w;
            float e0 = fexp2(fmaxf(y0, ALPHA_SLOPE * y0));
            float e1 = fexp2(fmaxf(y1, ALPHA_SLOPE * y1));
            float e2 = fexp2(fmaxf(y2, ALPHA_SLOPE * y2));
            float e3 = fexp2(fmaxf(y3, ALPHA_SLOPE * y3));
            float e4 = fexp2(fmaxf(y4, ALPHA_SLOPE * y4));
            float e5 = fexp2(fmaxf(y5, ALPHA_SLOPE * y5));
            float e6 = fexp2(fmaxf(y6, ALPHA_SLOPE * y6));
            float e7 = fexp2(fmaxf(y7, ALPHA_SLOPE * y7));
            float w0 = (mb &   1u) ? e0 : EXP_M10;
            float w1 = (mb &   2u) ? e1 : EXP_M10;
            float w2 = (mb &   4u) ? e2 : EXP_M10;
            float w3 = (mb &   8u) ? e3 : EXP_M10;
            float w4 = (mb &  16u) ? e4 : EXP_M10;
            float w5 = (mb &  32u) ? e5 : EXP_M10;
            float w6 = (mb &  64u) ? e6 : EXP_M10;
            float w7 = (mb & 128u) ? e7 : EXP_M10;

            union { unsigned int u[4]; s16x8 v; } af;
            af.u[0] = cvtpk(w0, w1);
            af.u[1] = cvtpk(w2, w3);
            af.u[2] = cvtpk(w4, w5);
            af.u[3] = cvtpk(w6, w7);

            const int cc = c0 + kk * 32;
            s16x8 b0 = *(const s16x8*)(h0b + cc);
            s16x8 b1 = *(const s16x8*)(h1b + cc);
            s16x8 b2 = *(const s16x8*)(h2b + cc);
            s16x8 b3 = *(const s16x8*)(h3b + cc);

            acc0 = __builtin_amdgcn_mfma_f32_16x16x32_bf16(af.v, b0,   acc0, 0, 0, 0);
            acc1 = __builtin_amdgcn_mfma_f32_16x16x32_bf16(af.v, b1,   acc1, 0, 0, 0);
            acc2 = __builtin_amdgcn_mfma_f32_16x16x32_bf16(af.v, b2,   acc2, 0, 0, 0);
            acc3 = __builtin_amdgcn_mfma_f32_16x16x32_bf16(af.v, b3,   acc3, 0, 0, 0);
            accD = __builtin_amdgcn_mfma_f32_16x16x32_bf16(af.v, bden, accD, 0, 0, 0);
        }
    }

    // epilogue: C/D layout col=lane&15, row=quad*4+reg -> direct coalesced slab write
    float* slab = slabs + (size_t)jc * ((size_t)NN * CP) + (size_t)row0 * CP;
    #pragma unroll
    for (int r = 0; r < 4; ++r) {
        const int ro = quad * 4 + r;
        slab[ro * CP +  0 + m] = acc0[r];
        slab[ro * CP + 16 + m] = acc1[r];
        slab[ro * CP + 32 + m] = acc2[r];
        slab[ro * CP + 48 + m] = acc3[r];
        if (m == 0) slab[ro * CP + 64] = accD[r];
    }
}

// ---------------- Kernel 3: reduce chunks, normalize, ELU --------------------------
__global__ __launch_bounds__(256) void k_norm(
    const float* __restrict__ slabs, float* __restrict__ out)
{
    int gid = blockIdx.x * 256 + threadIdx.x;
    int i = gid >> 6, k = gid & 63;
    float num = 0.f, den = 0.f;
    #pragma unroll
    for (int jc = 0; jc < JC; ++jc) {
        const float* rowp = slabs + (size_t)jc * ((size_t)NN * CP) + (size_t)i * CP;
        num += rowp[k];
        den += rowp[64];
    }
    float v = num / den;
    out[gid] = (v > 0.f) ? v : (__expf(v) - 1.f);
}

// ---------------- launch -----------------------------------------------------------
extern "C" void kernel_launch(void* const* d_in, const int* in_sizes, int n_in,
                              void* d_out, int out_size, void* d_ws, size_t ws_size,
                              hipStream_t stream) {
    const float* input = (const float*)d_in[0];
    const int*   adj   = (const int*)d_in[1];
    const float* W     = (const float*)d_in[2];
    const float* a     = (const float*)d_in[3];
    float* out = (float*)d_out;

    char* ws = (char*)d_ws;
    float* slabs = (float*)ws;
    size_t off = (size_t)JC * NN * CP * sizeof(float);          // 17.8 MB
    unsigned short* htg = (unsigned short*)(ws + off);
    off += (size_t)FOUT * NN * sizeof(unsigned short);          // 1 MB
    float* s1 = (float*)(ws + off); off += NN * sizeof(float);
    float* s2 = (float*)(ws + off); off += NN * sizeof(float);
    unsigned int* mask = (unsigned int*)(ws + off);             // 8 MB

    k_pack<<<2048, 256, 0, stream>>>(adj, mask);
    k_h   <<<NN / 16, 256, 0, stream>>>(input, W, a, htg, s1, s2);
    k_attn<<<(NN / 16 / 4) * JC, 256, 0, stream>>>(mask, htg, s1, s2, slabs);
    k_norm<<<NN * FOUT / 256, 256, 0, stream>>>(slabs, out);
}

// Round 2
// 391.042 us; speedup vs baseline: 1.1869x; 1.1869x over previous
//
#include <hip/hip_runtime.h>
#include <hip/hip_bf16.h>
#include <cstdint>
#include <cstddef>

#define NN 8192
#define FIN 256
#define FOUT 64
#define ALPHA_SLOPE 0.2f
#define EXP_M10 4.5399929762484854e-05f   // exp(-10)

#define JSPLIT 2
#define STRIP 128
#define NSTRIP ((NN / JSPLIT) / STRIP)    // 32
#define WPITCH 272                        // bytes per w-row in LDS (256 data + 16 pad)
#define HPITCH 272                        // bytes per htg-row in LDS
#define CP 68                             // slab column pitch (floats)

typedef short s16x8 __attribute__((ext_vector_type(8)));
typedef float f32x4 __attribute__((ext_vector_type(4)));
typedef int   i32x4 __attribute__((ext_vector_type(4)));

__device__ __forceinline__ unsigned short f2bf(float x) {
    union { float f; uint32_t u; } v; v.f = x;
    uint32_t u = v.u;
    return (unsigned short)((u + 0x7FFFu + ((u >> 16) & 1u)) >> 16);  // RNE
}

__device__ __forceinline__ unsigned int pk2(float lo, float hi) {
    return (unsigned int)f2bf(lo) | ((unsigned int)f2bf(hi) << 16);
}

// ---------------- Kernel 1: h = input@W, s1 = h@a1, s2 = h@a2, htg = bf16(h)^T ----
__global__ __launch_bounds__(256) void k_h(
    const float* __restrict__ input, const float* __restrict__ W,
    const float* __restrict__ a,
    unsigned short* __restrict__ htg, float* __restrict__ s1, float* __restrict__ s2)
{
    __shared__ __align__(16) unsigned short tile[64][28];
    const int wid  = threadIdx.x >> 6;
    const int lane = threadIdx.x & 63;
    const int i0   = blockIdx.x * 16;
    const int r0   = wid * 4;
    const float* inb = input + (size_t)(i0 + r0) * FIN;

    float acc0 = 0.f, acc1 = 0.f, acc2 = 0.f, acc3 = 0.f;
    #pragma unroll 4
    for (int c = 0; c < FIN; c += 4) {
        float w0 = W[(c + 0) * FOUT + lane];
        float w1 = W[(c + 1) * FOUT + lane];
        float w2 = W[(c + 2) * FOUT + lane];
        float w3 = W[(c + 3) * FOUT + lane];
        float4 x0 = *(const float4*)(inb + 0 * FIN + c);
        float4 x1 = *(const float4*)(inb + 1 * FIN + c);
        float4 x2 = *(const float4*)(inb + 2 * FIN + c);
        float4 x3 = *(const float4*)(inb + 3 * FIN + c);
        acc0 = fmaf(x0.x, w0, fmaf(x0.y, w1, fmaf(x0.z, w2, fmaf(x0.w, w3, acc0))));
        acc1 = fmaf(x1.x, w0, fmaf(x1.y, w1, fmaf(x1.z, w2, fmaf(x1.w, w3, acc1))));
        acc2 = fmaf(x2.x, w0, fmaf(x2.y, w1, fmaf(x2.z, w2, fmaf(x2.w, w3, acc2))));
        acc3 = fmaf(x3.x, w0, fmaf(x3.y, w1, fmaf(x3.z, w2, fmaf(x3.w, w3, acc3))));
    }

    const float a1v = a[lane], a2v = a[FOUT + lane];
    float accs[4] = {acc0, acc1, acc2, acc3};
    #pragma unroll
    for (int r = 0; r < 4; ++r) {
        float v1 = accs[r] * a1v;
        float v2 = accs[r] * a2v;
        #pragma unroll
        for (int off = 32; off; off >>= 1) {
            v1 += __shfl_xor(v1, off);
            v2 += __shfl_xor(v2, off);
        }
        if (lane == 0) { s1[i0 + r0 + r] = v1; s2[i0 + r0 + r] = v2; }
        tile[lane][r0 + r] = f2bf(accs[r]);
    }
    __syncthreads();

    const int feat = threadIdx.x >> 2;
    const int cg   = (threadIdx.x & 3) * 4;
    uint2 q = *(const uint2*)&tile[feat][cg];
    *(uint2*)(htg + (size_t)feat * NN + i0 + cg) = q;
}

// ---------------- Kernel 2: traffic-minimized fused attention ----------------------
// Block: 32 rows x 4096-col j-half, 512 threads (8 waves), 2 blocks/CU.
// Per 128-col strip (double-buffered, pipelined one ahead through VGPRs):
//   stage: w = bf16(exp(masked lrelu(s1_i+s2_j))) computed ONCE per element -> LDS;
//          htg strip (64 feats x 128 cols) -> LDS (shared by all 8 waves -> halves
//          the dominant htg re-read traffic vs 16-row blocks).
//   mfma : wave (rowgrp, kkpair, featgrp) does 2 kk x (2 or 3) MFMA from LDS.
// Epilogue: LDS reduction over kk-waves -> slab (denominator via B=[1,0..] MFMA).
__global__ __launch_bounds__(512, 4) void k_attn(
    const int* __restrict__ adj,
    const unsigned short* __restrict__ htg,
    const float* __restrict__ s1g, const float* __restrict__ s2g,
    float* __restrict__ slabs)
{
    __shared__ __align__(16) unsigned char wbuf[2][32 * WPITCH];   // 17408 B
    __shared__ __align__(16) unsigned char hbuf[2][64 * HPITCH];   // 34816 B

    const int t    = threadIdx.x;
    const int wid  = t >> 6;
    const int lane = t & 63;
    const int bi   = blockIdx.x >> 1;
    const int js   = blockIdx.x & 1;
    const int i0   = bi * 32;
    const int jbase = js * (NN / JSPLIT);
    const int m    = lane & 15;
    const int quad = lane >> 4;
    const int rg   = wid >> 2;          // row group: rows rg*16..rg*16+15
    const int kp   = (wid >> 1) & 1;    // kk pair: kk = kp*2 + {0,1}
    const int fg   = wid & 1;           // feature group: feats fg*32..fg*32+31 (+den)

    // fixed staging coordinates
    const int srow  = t >> 4;           // 0..31  (adj/w row)
    const int scol  = (t & 15) * 8;     // 0..120 (8 cols per thread)
    const int sfeat = t >> 3;           // 0..63  (htg row)
    const int scol2 = (t & 7) * 16;     // 0..112 (16 cols per thread)
    const float s1v = s1g[i0 + srow];

    const short bd = (m == 0) ? (short)0x3F80 : (short)0;   // bf16 1.0 / 0
    const s16x8 bden = {bd, bd, bd, bd, bd, bd, bd, bd};

    f32x4 accA = {0,0,0,0}, accB = {0,0,0,0}, accD = {0,0,0,0};

    const int* adjrow = adj + (size_t)(i0 + srow) * NN + jbase;
    const unsigned short* hrow = htg + (size_t)sfeat * NN + jbase;

    // ---- prologue: stage strip 0 into buffer 0 ----
    {
        i32x4  a0 = *(const i32x4*)(adjrow + scol);
        i32x4  a1 = *(const i32x4*)(adjrow + scol + 4);
        float4 v0 = *(const float4*)(s2g + jbase + scol);
        float4 v1 = *(const float4*)(s2g + jbase + scol + 4);
        s16x8  h0 = *(const s16x8*)(hrow + scol2);
        s16x8  h1 = *(const s16x8*)(hrow + scol2 + 8);

        float x0=s1v+v0.x, x1=s1v+v0.y, x2=s1v+v0.z, x3=s1v+v0.w;
        float x4=s1v+v1.x, x5=s1v+v1.y, x6=s1v+v1.z, x7=s1v+v1.w;
        float w0=(a0.x>0)?__expf(fmaxf(x0,ALPHA_SLOPE*x0)):EXP_M10;
        float w1=(a0.y>0)?__expf(fmaxf(x1,ALPHA_SLOPE*x1)):EXP_M10;
        float w2=(a0.z>0)?__expf(fmaxf(x2,ALPHA_SLOPE*x2)):EXP_M10;
        float w3=(a0.w>0)?__expf(fmaxf(x3,ALPHA_SLOPE*x3)):EXP_M10;
        float w4=(a1.x>0)?__expf(fmaxf(x4,ALPHA_SLOPE*x4)):EXP_M10;
        float w5=(a1.y>0)?__expf(fmaxf(x5,ALPHA_SLOPE*x5)):EXP_M10;
        float w6=(a1.z>0)?__expf(fmaxf(x6,ALPHA_SLOPE*x6)):EXP_M10;
        float w7=(a1.w>0)?__expf(fmaxf(x7,ALPHA_SLOPE*x7)):EXP_M10;
        uint4 pk = { pk2(w0,w1), pk2(w2,w3), pk2(w4,w5), pk2(w6,w7) };
        *(uint4*)&wbuf[0][srow * WPITCH + scol * 2] = pk;
        *(s16x8*)&hbuf[0][sfeat * HPITCH + scol2 * 2] = h0;
        *(s16x8*)&hbuf[0][sfeat * HPITCH + scol2 * 2 + 16] = h1;
    }
    __syncthreads();

    for (int s = 0; s < NSTRIP; ++s) {
        const int cur = s & 1, nxt = cur ^ 1;
        const bool more = (s + 1 < NSTRIP);

        // (a) issue next strip's global loads (no waits yet)
        i32x4 a0, a1; float4 v0, v1; s16x8 h0, h1;
        if (more) {
            const int j0n = (s + 1) * STRIP;
            a0 = *(const i32x4*)(adjrow + j0n + scol);
            a1 = *(const i32x4*)(adjrow + j0n + scol + 4);
            v0 = *(const float4*)(s2g + jbase + j0n + scol);
            v1 = *(const float4*)(s2g + jbase + j0n + scol + 4);
            h0 = *(const s16x8*)(hrow + j0n + scol2);
            h1 = *(const s16x8*)(hrow + j0n + scol2 + 8);
        }

        // (b) compute current strip from LDS
        #pragma unroll
        for (int kq = 0; kq < 2; ++kq) {
            const int kk = kp * 2 + kq;
            const int cb = (kk * 32 + quad * 8) * 2;   // byte col offset
            s16x8 af = *(const s16x8*)&wbuf[cur][(rg * 16 + m) * WPITCH + cb];
            const unsigned char* hb = &hbuf[cur][cb];
            if (fg == 0) {
                s16x8 b0 = *(const s16x8*)(hb + (m +  0) * HPITCH);
                s16x8 b1 = *(const s16x8*)(hb + (m + 16) * HPITCH);
                accA = __builtin_amdgcn_mfma_f32_16x16x32_bf16(af, b0, accA, 0, 0, 0);
                accB = __builtin_amdgcn_mfma_f32_16x16x32_bf16(af, b1, accB, 0, 0, 0);
            } else {
                s16x8 b2 = *(const s16x8*)(hb + (m + 32) * HPITCH);
                s16x8 b3 = *(const s16x8*)(hb + (m + 48) * HPITCH);
                accA = __builtin_amdgcn_mfma_f32_16x16x32_bf16(af, b2,   accA, 0, 0, 0);
                accB = __builtin_amdgcn_mfma_f32_16x16x32_bf16(af, b3,   accB, 0, 0, 0);
                accD = __builtin_amdgcn_mfma_f32_16x16x32_bf16(af, bden, accD, 0, 0, 0);
            }
        }

        // (c) finish staging next strip (waits for (a) loads happen here)
        if (more) {
            float x0=s1v+v0.x, x1=s1v+v0.y, x2=s1v+v0.z, x3=s1v+v0.w;
            float x4=s1v+v1.x, x5=s1v+v1.y, x6=s1v+v1.z, x7=s1v+v1.w;
            float w0=(a0.x>0)?__expf(fmaxf(x0,ALPHA_SLOPE*x0)):EXP_M10;
            float w1=(a0.y>0)?__expf(fmaxf(x1,ALPHA_SLOPE*x1)):EXP_M10;
            float w2=(a0.z>0)?__expf(fmaxf(x2,ALPHA_SLOPE*x2)):EXP_M10;
            float w3=(a0.w>0)?__expf(fmaxf(x3,ALPHA_SLOPE*x3)):EXP_M10;
            float w4=(a1.x>0)?__expf(fmaxf(x4,ALPHA_SLOPE*x4)):EXP_M10;
            float w5=(a1.y>0)?__expf(fmaxf(x5,ALPHA_SLOPE*x5)):EXP_M10;
            float w6=(a1.z>0)?__expf(fmaxf(x6,ALPHA_SLOPE*x6)):EXP_M10;
            float w7=(a1.w>0)?__expf(fmaxf(x7,ALPHA_SLOPE*x7)):EXP_M10;
            uint4 pk = { pk2(w0,w1), pk2(w2,w3), pk2(w4,w5), pk2(w6,w7) };
            *(uint4*)&wbuf[nxt][srow * WPITCH + scol * 2] = pk;
            *(s16x8*)&hbuf[nxt][sfeat * HPITCH + scol2 * 2] = h0;
            *(s16x8*)&hbuf[nxt][sfeat * HPITCH + scol2 * 2 + 16] = h1;
        }
        __syncthreads();
    }

    // ---- epilogue: reduce kk-pair waves, write slab ----
    // red[8][16][34] floats = 17408 B, overlaid on hbuf (all reads done: final barrier passed)
    float* red = (float*)hbuf;
    float* myr = red + wid * (16 * 34);
    #pragma unroll
    for (int reg = 0; reg < 4; ++reg) {
        const int r = quad * 4 + reg;
        myr[r * 34 + m]      = accA[reg];
        myr[r * 34 + 16 + m] = accB[reg];
        if (fg == 1 && m == 0) myr[r * 34 + 32] = accD[reg];
    }
    __syncthreads();

    float* slab = slabs + (size_t)js * ((size_t)NN * CP);
    #pragma unroll
    for (int idx = t; idx < 32 * 64; idx += 512) {
        const int r = idx >> 6, c = idx & 63;
        const int rg2 = r >> 4, rr = r & 15;
        const int fg2 = c >> 5, lc = c & 31;
        float num = red[(rg2 * 4 + 0 + fg2) * 544 + rr * 34 + lc]
                  + red[(rg2 * 4 + 2 + fg2) * 544 + rr * 34 + lc];
        slab[(size_t)(i0 + r) * CP + c] = num;
        if (c == 0) {
            float den = red[(rg2 * 4 + 1) * 544 + rr * 34 + 32]
                      + red[(rg2 * 4 + 3) * 544 + rr * 34 + 32];
            slab[(size_t)(i0 + r) * CP + 64] = den;
        }
    }
}

// ---------------- Kernel 3: reduce splits, normalize, ELU --------------------------
__global__ __launch_bounds__(256) void k_norm(
    const float* __restrict__ slabs, float* __restrict__ out)
{
    int gid = blockIdx.x * 256 + threadIdx.x;
    int i = gid >> 6, k = gid & 63;
    float num = 0.f, den = 0.f;
    #pragma unroll
    for (int js = 0; js < JSPLIT; ++js) {
        const float* row = slabs + (size_t)js * ((size_t)NN * CP) + (size_t)i * CP;
        num += row[k];
        den += row[64];
    }
    float v = num / den;
    out[gid] = (v > 0.f) ? v : (__expf(v) - 1.f);
}

// ---------------- launch -----------------------------------------------------------
extern "C" void kernel_launch(void* const* d_in, const int* in_sizes, int n_in,
                              void* d_out, int out_size, void* d_ws, size_t ws_size,
                              hipStream_t stream) {
    const float* input = (const float*)d_in[0];
    const int*   adj   = (const int*)d_in[1];
    const float* W     = (const float*)d_in[2];
    const float* a     = (const float*)d_in[3];
    float* out = (float*)d_out;

    char* ws = (char*)d_ws;
    float* slabs = (float*)ws;
    size_t off = (size_t)JSPLIT * NN * CP * sizeof(float);      // 4.5 MB
    unsigned short* htg = (unsigned short*)(ws + off);
    off += (size_t)FOUT * NN * sizeof(unsigned short);          // 1 MB
    float* s1 = (float*)(ws + off); off += NN * sizeof(float);
    float* s2 = (float*)(ws + off);

    k_h   <<<NN / 16, 256, 0, stream>>>(input, W, a, htg, s1, s2);
    k_attn<<<(NN / 32) * JSPLIT, 512, 0, stream>>>(adj, htg, s1, s2, slabs);
    k_norm<<<NN * FOUT / 256, 256, 0, stream>>>(slabs, out);
}